// Round 1
// baseline (1595.526 us; speedup 1.0000x reference)
//
#include <hip/hip_runtime.h>
#include <math.h>

#define NTAU 82
#define TMIN 28
#define S_TOT 5617
#define TF 6000
#define BATCH 4
#define WMAX 28
#define AP 84            // A/fb row pitch: 82 + 2 pad; 336B = 21*16 -> float4-aligned rows
#define NTHREADS 1024
#define NCHUNK 215
#define CHUNK_G (WMAX * AP)   // 2352 floats per chunk of A-history
#define NCAP (WMAX * NTAU)    // 2296 capture slots per chunk (one per (row, block))
#define NNR 3321              // nonreset slots = sum_b (tau_b - 28) = 82*81/2

// ws layout (float offsets)
#define TRANS_OFF 0            // 82*82
#define BLP_OFF   8192         // 4*6000
#define NBLP_OFF  32768        // 4*6000
#define AH_OFF    57344        // 4 * 215 * 2352 A-history (backtrace only)

typedef float v2f __attribute__((ext_vector_type(2)));

__device__ __forceinline__ int first_of(int bb) { return bb * (55 + bb) / 2; }

__device__ __forceinline__ float logsig(float x) {
    return -(fmaxf(-x, 0.0f) + log1pf(expf(-fabsf(x))));
}

// ---------------- setup kernel 1: trans_log in fp64, cast to fp32 -------------
__global__ void k_trans(float* __restrict__ ws) {
    int i = blockIdx.x;
    int j = threadIdx.x;
    __shared__ double sh[128];
    double raw = 0.0, e = 0.0;
    double ti = 28.0 + (double)i;
    if (j < NTAU) {
        double tj = 28.0 + (double)j;
        raw = -100.0 * fabs(tj / ti - 1.0);
        e = exp(raw);
    }
    sh[j] = e;
    __syncthreads();
    for (int st = 64; st > 0; st >>= 1) {
        if (j < st) sh[j] += sh[j + st];
        __syncthreads();
    }
    double lse = log(sh[0]);
    if (j < NTAU) ws[TRANS_OFF + i * NTAU + j] = (float)(raw - lse);
}

// ---------------- setup kernel 2: emissions + zero output ---------------------
__global__ void k_emis(const float* __restrict__ logit, float* __restrict__ ws,
                       float* __restrict__ out) {
    int idx = blockIdx.x * blockDim.x + threadIdx.x;
    if (idx < BATCH * TF) {
        float x = logit[idx];
        ws[BLP_OFF + idx]  = logsig(x);
        ws[NBLP_OFF + idx] = logsig(-x);
        out[idx] = 0.0f;
    }
}

// ---------------- main kernel: ONE workgroup per batch ------------------------
// Fused both tempo-parity halves into a single 1024-thread WG: the L3 exchange
// (sc1 publish drain + flag poll + partner import) and 2 of 5 barriers are
// gone. Non-redundant ph2 mapping: 4 overlapping i-segments (width 22, bases
// 0/20/40/60 -> float4-aligned; overlap harmless for max) x 41 j-pairs x 6
// row-groups. All emission chains stay exact-sequential (bit-exact vs ref);
// max-plus is single-add + max (exactly associative).
__global__ __attribute__((amdgpu_flat_work_group_size(NTHREADS, NTHREADS),
                          amdgpu_waves_per_eu(4, 4)))
void k_viterbi(const float* __restrict__ logit,
               const float* __restrict__ transg,
               const float* __restrict__ blp_all,
               const float* __restrict__ nblp_all,
               float* __restrict__ Ah_all,
               float* __restrict__ out) {
    const int tid = threadIdx.x;
    const int b   = blockIdx.x;

    const float* blp  = blp_all  + b * TF;
    const float* nblp = nblp_all + b * TF;
    float* Ah = Ah_all + (size_t)b * (NCHUNK * CHUNK_G);

    __shared__ float V[S_TOT];                       // all 5617 state slots
    __shared__ __align__(16) float A_lds[CHUNK_G];   // capture rows [28][84]
    __shared__ __align__(16) float fb[CHUNK_G];      // from_beat  [28][84]
    __shared__ __align__(16) float win_nb[4][WMAX];
    __shared__ __align__(16) float win_b[4][WMAX];
    __shared__ float wv[16];
    __shared__ int   wi[16];
    __shared__ int   sstate;

    // ---- ph2 mapping: quad lanes = iseg; 41 j-pairs; 6 row-groups -----------
    const int iseg = tid & 3;
    const int jp   = (tid >> 2) % 41;
    const int rg   = tid / 164;          // 0..5 for active threads
    const bool p2act = (tid < 984);      // 4*41*6
    const int ib = iseg * 20;            // i-window [ib, ib+22); segs overlap
    const int j0 = 2 * jp;

    float tr0[22], tr1[22];
#pragma unroll
    for (int k = 0; k < 22; ++k) { tr0[k] = -1.0e30f; tr1[k] = -1.0e30f; }
    if (p2act) {
#pragma unroll
        for (int k = 0; k < 22; ++k) {
            tr0[k] = transg[(ib + k) * NTAU + j0];
            tr1[k] = transg[(ib + k) * NTAU + j0 + 1];
        }
    }

    // ---- capture slots: slot = ro*82 + blk; 3 per thread --------------------
    // Slot (ro, blk): block blk's last-position state at chunk-row ro; it
    // resets (wraps to pos 0) at row ro+1. rr trajectory: ro, +=28 mod tau.
    int cro[3], coff[3], cva[3], clim[3], ctau[3];
    bool cvalid[3];
#pragma unroll
    for (int q = 0; q < 3; ++q) {
        const int slot = tid + q * NTHREADS;
        cvalid[q] = (slot < NCAP);
        if (cvalid[q]) {
            const int ro  = slot / NTAU;
            const int blk = slot - ro * NTAU;
            const int fo  = first_of(blk);
            cro[q]  = ro;
            coff[q] = ro * AP + blk;
            cva[q]  = fo + ro;           // rr starts at ro
            ctau[q] = TMIN + blk;
            clim[q] = fo + ctau[q];
        } else {
            cro[q] = 0; coff[q] = 0; cva[q] = 0; ctau[q] = TMIN; clim[q] = TMIN;
        }
    }

    // ---- nonreset slots: flat f over 3321; 4 per thread ---------------------
    // block b contributes b slots (tau-28 = b); base T(b) = b(b-1)/2.
    int nva[4], nlim[4], ntau[4];
    bool nvalid[4];
#pragma unroll
    for (int q = 0; q < 4; ++q) {
        const int f = tid + q * NTHREADS;
        nvalid[q] = (f < NNR);
        if (nvalid[q]) {
            int lo = 1, hi = NTAU - 1;
            while (lo < hi) { int mid = (lo + hi + 1) >> 1;
                              if (mid * (mid - 1) / 2 <= f) lo = mid; else hi = mid - 1; }
            const int m  = f - lo * (lo - 1) / 2;    // 0 <= m < lo
            const int fo = first_of(lo);
            nva[q]  = fo + TMIN + m;                 // r starts at 28+m
            ntau[q] = TMIN + lo;
            nlim[q] = fo + ntau[q];
        } else {
            nva[q] = 0; ntau[q] = TMIN; nlim[q] = TMIN;   // pinned at 0, no store
        }
    }

    // ---- V init -------------------------------------------------------------
    const float logS = (float)log((double)S_TOT);
    const float b0 = blp[0], n0 = nblp[0];
    for (int g = tid; g < S_TOT; g += NTHREADS) {
        int lo = 0, hi = NTAU - 1;
        while (lo < hi) { int mid = (lo + hi + 1) >> 1;
                          if (first_of(mid) <= g) lo = mid; else hi = mid - 1; }
        const int r = g - first_of(lo);
        V[g] = ((r == TMIN + lo - 1) ? b0 : n0) - logS;
    }

    auto winload = [&](int cc) {
        if (cc < NCHUNK && tid < WMAX) {
            const int gt = 1 + cc * WMAX + tid;
            win_nb[cc & 3][tid] = (gt < TF) ? nblp[gt] : 0.0f;
            win_b [cc & 3][tid] = (gt < TF) ? blp[gt]  : 0.0f;
        }
    };
    winload(0);
    winload(1);
    __syncthreads();

#define PH2P(av, aw, t0a, t0b, t1a, t1b) { \
    float x0 = (av) + (t0a); float y0 = (aw) + (t0b); \
    m0 = fmaxf(fmaxf(m0, x0), y0); \
    float x1 = (av) + (t1a); float y1 = (aw) + (t1b); \
    m1 = fmaxf(fmaxf(m1, x1), y1); }

    float cv[3];
    for (int c = 0; c < NCHUNK; ++c) {
        const int buf = c & 3;
        float* AhC = Ah + (size_t)c * CHUNK_G;

        winload(c + 2);

        // ---- capture: C = V + nb[0..ro-1] (exact sequential); stage in LDS --
#pragma unroll
        for (int q = 0; q < 3; ++q) {
            float s = V[cva[q]];
            const int ro = cro[q];
            for (int tt = 0; tt < ro; ++tt) s += win_nb[buf][tt];
            cv[q] = s;
            if (cvalid[q]) A_lds[coff[q]] = s;
        }
        __syncthreads();   // B1: A_lds rows complete

        // ---- publish capture rows to global history (backtrace only); the
        //      plain-store drain lands at B2, hidden under ph2 ----------------
#pragma unroll
        for (int q = 0; q < 3; ++q)
            if (cvalid[q]) AhC[coff[q]] = cv[q];

        // ---- ph2: from_beat[j] = max_i (A[row][i] + trans[i][j]) ------------
        if (p2act) {
#pragma unroll
            for (int u = 0; u < 5; ++u) {
                const int tl = rg + 6 * u;
                if (tl < WMAX) {
                    const float* ar = &A_lds[tl * AP + ib];
                    const float4 a0 = ((const float4*)ar)[0];
                    const float4 a1 = ((const float4*)ar)[1];
                    const float4 a2 = ((const float4*)ar)[2];
                    const float4 a3 = ((const float4*)ar)[3];
                    const float4 a4 = ((const float4*)ar)[4];
                    const v2f    a5 = *(const v2f*)(ar + 20);
                    float m0 = -INFINITY, m1 = -INFINITY;
                    PH2P(a0.x, a0.y, tr0[0],  tr0[1],  tr1[0],  tr1[1])
                    PH2P(a0.z, a0.w, tr0[2],  tr0[3],  tr1[2],  tr1[3])
                    PH2P(a1.x, a1.y, tr0[4],  tr0[5],  tr1[4],  tr1[5])
                    PH2P(a1.z, a1.w, tr0[6],  tr0[7],  tr1[6],  tr1[7])
                    PH2P(a2.x, a2.y, tr0[8],  tr0[9],  tr1[8],  tr1[9])
                    PH2P(a2.z, a2.w, tr0[10], tr0[11], tr1[10], tr1[11])
                    PH2P(a3.x, a3.y, tr0[12], tr0[13], tr1[12], tr1[13])
                    PH2P(a3.z, a3.w, tr0[14], tr0[15], tr1[14], tr1[15])
                    PH2P(a4.x, a4.y, tr0[16], tr0[17], tr1[16], tr1[17])
                    PH2P(a4.z, a4.w, tr0[18], tr0[19], tr1[18], tr1[19])
                    PH2P(a5.x, a5.y, tr0[20], tr0[21], tr1[20], tr1[21])
                    m0 = fmaxf(m0, __shfl_xor(m0, 1));
                    m1 = fmaxf(m1, __shfl_xor(m1, 1));
                    m0 = fmaxf(m0, __shfl_xor(m0, 2));
                    m1 = fmaxf(m1, __shfl_xor(m1, 2));
                    if (iseg == 0) *(v2f*)&fb[tl * AP + j0] = v2f{m0, m1};
                }
            }
        }

        // ---- nonreset slots: 28 sequential adds (exact) ---------------------
        {
            v2f x01 = v2f{V[nva[0]], V[nva[1]]};
            v2f x23 = v2f{V[nva[2]], V[nva[3]]};
#pragma unroll
            for (int tt = 0; tt < WMAX; ++tt) {
                const float w = win_nb[buf][tt];
                x01 += v2f{w, w};
                x23 += v2f{w, w};
            }
            V[nva[0]] = x01.x;
            V[nva[1]] = x01.y;
            V[nva[2]] = x23.x;
            if (nvalid[3]) V[nva[3]] = x23.y;
        }
        __syncthreads();   // B2: fb ready; nonreset V written

        // ---- suffix: entry + remaining adds (exact sequential) --------------
#pragma unroll
        for (int q = 0; q < 3; ++q) {
            if (cvalid[q]) {
                const int ro = cro[q];
                float e = fb[coff[q]] + win_b[buf][ro];
                for (int tt = ro + 1; tt < WMAX; ++tt) e += win_nb[buf][tt];
                // last chunk (real width 7): resets at ro>=7 must not happen;
                // capture C == exact final value there (pad adds are +0.0)
                const bool keepC = (c == NCHUNK - 1) && (ro >= 7);
                V[cva[q]] = keepC ? cv[q] : e;
            }
            cva[q] += WMAX; if (cva[q] >= clim[q]) cva[q] -= ctau[q];
        }
#pragma unroll
        for (int q = 0; q < 4; ++q) {
            nva[q] += WMAX; if (nva[q] >= nlim[q]) nva[q] -= ntau[q];
        }
        __syncthreads();   // B3: V stable for next chunk
    }
#undef PH2P

    // ---- final argmax over all of V; tie -> smallest global state index ----
    float bvv = -INFINITY; int bss = 0x7fffffff;
    for (int g = tid; g < S_TOT; g += NTHREADS) {
        int lo = 0, hi = NTAU - 1;
        while (lo < hi) { int mid = (lo + hi + 1) >> 1;
                          if (first_of(mid) <= g) lo = mid; else hi = mid - 1; }
        const int fo  = first_of(lo);
        const int r   = g - fo;
        const int tau = TMIN + lo;
        const int p   = (5998 - r) % tau;
        const int s   = fo + p;
        const float v = V[g];
        if (v > bvv || (v == bvv && s < bss)) { bvv = v; bss = s; }
    }
#pragma unroll
    for (int d = 1; d < 64; d <<= 1) {
        const float ov = __shfl_xor(bvv, d);
        const int   os = __shfl_xor(bss, d);
        if (ov > bvv || (ov == bvv && os < bss)) { bvv = ov; bss = os; }
    }
    if ((tid & 63) == 0) { wv[tid >> 6] = bvv; wi[tid >> 6] = bss; }
    __syncthreads();
    if (tid == 0) {
        float bv = wv[0]; int bs = wi[0];
#pragma unroll
        for (int k = 1; k < 16; ++k)
            if (wv[k] > bv || (wv[k] == bv && wi[k] < bs)) { bv = wv[k]; bs = wi[k]; }
        sstate = bs;
    }
    __syncthreads();

    // ---- backtrace: wave 0 (Ah layout is now plain [chunk][row][84]) --------
    if (tid < 64) {
        const int lane = tid;
        int s = sstate;
        int t = TF - 1;
        for (int guard = 0; guard < 400; ++guard) {
            int lo = 0, hi = NTAU - 1;
            while (lo < hi) { int mid = (lo + hi + 1) >> 1;
                              if (first_of(mid) <= s) lo = mid; else hi = mid - 1; }
            const int j = lo;
            const int p = s - first_of(j);
            const int tb = t - p;
            if (tb < 0) break;
            if (lane == 0) {
                const float x = logit[b * TF + tb];
                const float act = 1.0f / (1.0f + expf(-x));
                if (act >= 0.05f) out[b * TF + tb] = 1.0f;
            }
            if (tb == 0) break;
            const int tq = tb - 1;
            const float* arow = Ah + (size_t)(tq / WMAX) * CHUNK_G + (tq % WMAX) * AP;
            float cvv = arow[lane] + transg[lane * NTAU + j];
            int ci = lane;
            if (lane < NTAU - 64) {
                const int i2 = 64 + lane;
                const float c2 = arow[i2] + transg[i2 * NTAU + j];
                if (c2 > cvv) { cvv = c2; ci = i2; }
            }
#pragma unroll
            for (int d = 1; d < 64; d <<= 1) {
                const float ov = __shfl_xor(cvv, d, 64);
                const int   oi = __shfl_xor(ci, d, 64);
                if (ov > cvv || (ov == cvv && oi < ci)) { cvv = ov; ci = oi; }
            }
            s = first_of(ci) + (TMIN + ci) - 1;   // last_idx[i*]
            t = tb - 1;
        }
    }
}

extern "C" void kernel_launch(void* const* d_in, const int* in_sizes, int n_in,
                              void* d_out, int out_size, void* d_ws, size_t ws_size,
                              hipStream_t stream) {
    const float* logit = (const float*)d_in[0];
    float* out = (float*)d_out;
    float* ws = (float*)d_ws;
    k_trans<<<dim3(NTAU), dim3(128), 0, stream>>>(ws);
    k_emis<<<dim3((BATCH * TF + 255) / 256), dim3(256), 0, stream>>>(logit, ws, out);
    k_viterbi<<<dim3(BATCH), dim3(NTHREADS), 0, stream>>>(
        logit, ws + TRANS_OFF, ws + BLP_OFF, ws + NBLP_OFF, ws + AH_OFF, out);
}